// Round 1
// baseline (637.563 us; speedup 1.0000x reference)
//
#include <hip/hip_runtime.h>
#include <stdint.h>

#define B_ 4096
#define D_ 768
#define F_ 16384
#define M_ 256

typedef short bf16x8 __attribute__((ext_vector_type(8)));
typedef float f32x4 __attribute__((ext_vector_type(4)));

__device__ __forceinline__ unsigned short f2bf(float f) {
  union { float f; uint32_t u; } c; c.f = f;
  uint32_t u = c.u;
  uint32_t r = (u + 0x7FFFu + ((u >> 16) & 1u)) >> 16;
  return (unsigned short)r;
}

__device__ __forceinline__ void gl_lds16(const void* g, void* l) {
  __builtin_amdgcn_global_load_lds(
      (const __attribute__((address_space(1))) unsigned int*)g,
      (__attribute__((address_space(3))) unsigned int*)l, 16, 0, 0);
}

// ---------------- elementwise f32 -> bf16 cast (+optional f32 copy) ----------------
__global__ void cast_kernel(const float* __restrict__ in, unsigned short* __restrict__ out,
                            float* __restrict__ cpy, int n4) {
  int i = blockIdx.x * blockDim.x + threadIdx.x;
  if (i >= n4) return;
  float4 v = reinterpret_cast<const float4*>(in)[i];
  ushort4 u;
  u.x = f2bf(v.x); u.y = f2bf(v.y); u.z = f2bf(v.z); u.w = f2bf(v.w);
  reinterpret_cast<ushort4*>(out)[i] = u;
  if (cpy) reinterpret_cast<float4*>(cpy)[i] = v;
}

// ---------------- gemm_bt: C[M,N] = A[M,K] * B[N,K]^T  (both bf16 K-contiguous) ----
// EPI 0: store bf16 (+bias)   EPI 1: store f32 (+bias)   EPI 2: exp(c/temp) -> f32 + rowsum
template <int EPI>
__global__ __launch_bounds__(256, 2) void gemm_bt(
    const unsigned short* __restrict__ A, const unsigned short* __restrict__ Bm,
    const float* __restrict__ bias, float* __restrict__ Cf,
    unsigned short* __restrict__ Cb, int M, int N, int K,
    float* __restrict__ rowsum, const float* __restrict__ tptr) {
  __shared__ unsigned short As[128 * 32];
  __shared__ unsigned short Bs[128 * 32];
  const int tid = threadIdx.x, lane = tid & 63, wave = tid >> 6;
  const int m0 = blockIdx.y * 128, n0 = blockIdx.x * 128;
  const int wr = wave >> 1, wc = wave & 1;
  f32x4 acc[4][4] = {};

  for (int k0 = 0; k0 < K; k0 += 32) {
#pragma unroll
    for (int i = 0; i < 2; ++i) {
      int cb = (i * 4 + wave) * 64;
      int ch = cb + lane;
      int row = ch >> 2, ko = (ch & 3) * 8;
      gl_lds16(A + (size_t)(m0 + row) * K + k0 + ko, (char*)As + (size_t)cb * 16);
      gl_lds16(Bm + (size_t)(n0 + row) * K + k0 + ko, (char*)Bs + (size_t)cb * 16);
    }
    __syncthreads();
    bf16x8 a[4];
#pragma unroll
    for (int m = 0; m < 4; ++m)
      a[m] = *reinterpret_cast<const bf16x8*>(
          &As[(wr * 64 + m * 16 + (lane & 15)) * 32 + (lane >> 4) * 8]);
#pragma unroll
    for (int n = 0; n < 4; ++n) {
      bf16x8 b = *reinterpret_cast<const bf16x8*>(
          &Bs[(wc * 64 + n * 16 + (lane & 15)) * 32 + (lane >> 4) * 8]);
#pragma unroll
      for (int m = 0; m < 4; ++m)
        acc[m][n] = __builtin_amdgcn_mfma_f32_16x16x32_bf16(a[m], b, acc[m][n], 0, 0, 0);
    }
    __syncthreads();
  }

  const int rbase = m0 + wr * 64 + (lane >> 4) * 4;
  const int cbase = n0 + wc * 64 + (lane & 15);
  if (EPI == 2) {
    const float invt = 1.0f / tptr[0];
#pragma unroll
    for (int m = 0; m < 4; ++m) {
      float rs[4] = {0.f, 0.f, 0.f, 0.f};
#pragma unroll
      for (int n = 0; n < 4; ++n) {
        int col = cbase + n * 16;
#pragma unroll
        for (int r = 0; r < 4; ++r) {
          float e = __expf(acc[m][n][r] * invt);
          Cf[(size_t)(rbase + m * 16 + r) * N + col] = e;
          rs[r] += e;
        }
      }
#pragma unroll
      for (int r = 0; r < 4; ++r) {
        float s = rs[r];
        s += __shfl_xor(s, 1);
        s += __shfl_xor(s, 2);
        s += __shfl_xor(s, 4);
        s += __shfl_xor(s, 8);
        if ((lane & 15) == 0) atomicAdd(&rowsum[rbase + m * 16 + r], s);
      }
    }
  } else {
#pragma unroll
    for (int m = 0; m < 4; ++m) {
#pragma unroll
      for (int n = 0; n < 4; ++n) {
        int col = cbase + n * 16;
        float bv = bias[col];
#pragma unroll
        for (int r = 0; r < 4; ++r) {
          float v = acc[m][n][r] + bv;
          size_t idx = (size_t)(rbase + m * 16 + r) * N + col;
          if (EPI == 0) Cb[idx] = f2bf(v);
          else Cf[idx] = v;
        }
      }
    }
  }
}

// ---------------- V[16384,768] f32 -> Vt[768,16384] bf16 (LDS transpose) -----------
__global__ __launch_bounds__(256) void transpose_v(const float* __restrict__ V,
                                                   unsigned short* __restrict__ Vt) {
  __shared__ float t[64][65];
  int r0 = blockIdx.x * 64, c0 = blockIdx.y * 64;
  int tid = threadIdx.x;
  int lr = tid >> 4, lc4 = (tid & 15) * 4;
#pragma unroll
  for (int i = 0; i < 4; ++i) {
    float4 v = *reinterpret_cast<const float4*>(&V[(size_t)(r0 + i * 16 + lr) * D_ + c0 + lc4]);
    t[i * 16 + lr][lc4 + 0] = v.x;
    t[i * 16 + lr][lc4 + 1] = v.y;
    t[i * 16 + lr][lc4 + 2] = v.z;
    t[i * 16 + lr][lc4 + 3] = v.w;
  }
  __syncthreads();
#pragma unroll
  for (int i = 0; i < 4; ++i) {
    int oc = i * 16 + lr;  // column of V == row of Vt (c0+oc)
    ushort4 u;
    u.x = f2bf(t[lc4 + 0][oc]);
    u.y = f2bf(t[lc4 + 1][oc]);
    u.z = f2bf(t[lc4 + 2][oc]);
    u.w = f2bf(t[lc4 + 3][oc]);
    *reinterpret_cast<ushort4*>(&Vt[(size_t)(c0 + oc) * F_ + r0 + lc4]) = u;
  }
}

// ---------------- x_hat: reads E (unnorm), writes f=E/rowsum in place, ------------
// ---------------- accumulates partial[ks] = f_chunk @ V_chunk via MFMA ------------
#define KS 4
__global__ __launch_bounds__(512, 1) void xhat_kernel(
    float* __restrict__ Ef, const unsigned short* __restrict__ Vt,
    const float* __restrict__ rowsum, float* __restrict__ partial) {
  __shared__ unsigned short As2[64 * 32];
  __shared__ unsigned short Vs[768 * 32];
  const int tid = threadIdx.x, lane = tid & 63, wave = tid >> 6;
  const int ks = blockIdx.x, rb = blockIdx.y;
  const int r0 = rb * 64;
  const int kbeg = ks * (F_ / KS);
  const int wr = wave >> 2, wc = wave & 3;
  const int erow = tid >> 3, eko = (tid & 7) * 4;
  const float inv_rs = 1.0f / rowsum[r0 + erow];
  f32x4 acc[2][12] = {};

  for (int k0 = kbeg; k0 < kbeg + F_ / KS; k0 += 32) {
    // stage E tile: read f32, write normalized f back, bf16 into LDS
    size_t eidx = (size_t)(r0 + erow) * F_ + k0 + eko;
    float4 e = *reinterpret_cast<const float4*>(&Ef[eidx]);
    float4 f4 = make_float4(e.x * inv_rs, e.y * inv_rs, e.z * inv_rs, e.w * inv_rs);
    *reinterpret_cast<float4*>(&Ef[eidx]) = f4;
    ushort4 u;
    u.x = f2bf(f4.x); u.y = f2bf(f4.y); u.z = f2bf(f4.z); u.w = f2bf(f4.w);
    *reinterpret_cast<ushort4*>(&As2[erow * 32 + eko]) = u;
    // stage Vt tile [768 x 32] bf16 via global_load_lds (6 issues/wave)
#pragma unroll
    for (int j = 0; j < 6; ++j) {
      int cb = j * 512 + wave * 64;
      int ch = cb + lane;
      int vrow = ch >> 2, vko = (ch & 3) * 8;
      gl_lds16(Vt + (size_t)vrow * F_ + k0 + vko, (char*)Vs + (size_t)cb * 16);
    }
    __syncthreads();
    bf16x8 a[2];
#pragma unroll
    for (int m = 0; m < 2; ++m)
      a[m] = *reinterpret_cast<const bf16x8*>(
          &As2[(wr * 32 + m * 16 + (lane & 15)) * 32 + (lane >> 4) * 8]);
#pragma unroll
    for (int n = 0; n < 12; ++n) {
      bf16x8 b = *reinterpret_cast<const bf16x8*>(
          &Vs[(wc * 192 + n * 16 + (lane & 15)) * 32 + (lane >> 4) * 8]);
      acc[0][n] = __builtin_amdgcn_mfma_f32_16x16x32_bf16(a[0], b, acc[0][n], 0, 0, 0);
      acc[1][n] = __builtin_amdgcn_mfma_f32_16x16x32_bf16(a[1], b, acc[1][n], 0, 0, 0);
    }
    __syncthreads();
  }

  float* P = partial + (size_t)ks * B_ * D_;
#pragma unroll
  for (int m = 0; m < 2; ++m) {
    int rowb = r0 + wr * 32 + m * 16 + (lane >> 4) * 4;
#pragma unroll
    for (int n = 0; n < 12; ++n) {
      int col = wc * 192 + n * 16 + (lane & 15);
#pragma unroll
      for (int r = 0; r < 4; ++r)
        P[(size_t)(rowb + r) * D_ + col] = acc[m][n][r];
    }
  }
}

// ---------------- sum KS partials -> x_hat ----------------------------------------
__global__ void reduce_kernel(const float* __restrict__ partial, float* __restrict__ out,
                              int n4) {
  int i = blockIdx.x * blockDim.x + threadIdx.x;
  if (i >= n4) return;
  const float4* p = reinterpret_cast<const float4*>(partial);
  float4 a = p[i], b = p[i + n4], c = p[i + 2 * n4], d = p[i + 3 * n4];
  float4 s = make_float4(a.x + b.x + c.x + d.x, a.y + b.y + c.y + d.y,
                         a.z + b.z + c.z + d.z, a.w + b.w + c.w + d.w);
  reinterpret_cast<float4*>(out)[i] = s;
}

extern "C" void kernel_launch(void* const* d_in, const int* in_sizes, int n_in,
                              void* d_out, int out_size, void* d_ws, size_t ws_size,
                              hipStream_t stream) {
  const float* x = (const float*)d_in[0];
  const float* mb = (const float*)d_in[1];
  const float* Wq = (const float*)d_in[2];
  const float* bq = (const float*)d_in[3];
  const float* Wk = (const float*)d_in[4];
  const float* bk = (const float*)d_in[5];
  const float* Wv = (const float*)d_in[6];
  const float* bv = (const float*)d_in[7];
  const float* temp = (const float*)d_in[8];

  float* out_x = (float*)d_out;
  float* out_xhat = out_x + (size_t)B_ * D_;
  float* out_f = out_xhat + (size_t)B_ * D_;
  float* out_V = out_f + (size_t)B_ * F_;

  char* ws = (char*)d_ws;
  unsigned short* xb  = (unsigned short*)(ws + 0);         // 4096*768*2   = 6291456
  unsigned short* mbb = (unsigned short*)(ws + 6291456);   // 16384*768*2  = 25165824
  unsigned short* Wqb = (unsigned short*)(ws + 31457280);  // 256*768*2    = 393216
  unsigned short* Wkb = (unsigned short*)(ws + 31850496);  // 393216
  unsigned short* Wvb = (unsigned short*)(ws + 32243712);  // 768*768*2    = 1179648
  unsigned short* Qb  = (unsigned short*)(ws + 33423360);  // 4096*256*2   = 2097152
  unsigned short* Kb  = (unsigned short*)(ws + 35520512);  // 16384*256*2  = 8388608
  unsigned short* Vtb = (unsigned short*)(ws + 43909120);  // 768*16384*2  = 25165824
  float* rowsum       = (float*)(ws + 69074944);           // 4096*4       = 16384
  float* partial      = (float*)(ws + 69091328);           // 4*4096*768*4 = 50331648
  // total ws use: ~119.4 MB

  hipMemsetAsync(rowsum, 0, B_ * sizeof(float), stream);

  cast_kernel<<<(B_ * D_ / 4 + 255) / 256, 256, 0, stream>>>(x, xb, out_x, B_ * D_ / 4);
  cast_kernel<<<(F_ * D_ / 4 + 255) / 256, 256, 0, stream>>>(mb, mbb, nullptr, F_ * D_ / 4);
  cast_kernel<<<(M_ * D_ / 4 + 255) / 256, 256, 0, stream>>>(Wq, Wqb, nullptr, M_ * D_ / 4);
  cast_kernel<<<(M_ * D_ / 4 + 255) / 256, 256, 0, stream>>>(Wk, Wkb, nullptr, M_ * D_ / 4);
  cast_kernel<<<(D_ * D_ / 4 + 255) / 256, 256, 0, stream>>>(Wv, Wvb, nullptr, D_ * D_ / 4);

  dim3 blk(256);
  // Q = x @ Wq^T + bq  -> Qb (bf16)
  gemm_bt<0><<<dim3(M_ / 128, B_ / 128), blk, 0, stream>>>(xb, Wqb, bq, nullptr, Qb,
                                                           B_, M_, D_, nullptr, nullptr);
  // K = mb @ Wk^T + bk -> Kb (bf16)
  gemm_bt<0><<<dim3(M_ / 128, F_ / 128), blk, 0, stream>>>(mbb, Wkb, bk, nullptr, Kb,
                                                           F_, M_, D_, nullptr, nullptr);
  // V = mb @ Wv^T + bv -> out_V (f32)
  gemm_bt<1><<<dim3(D_ / 128, F_ / 128), blk, 0, stream>>>(mbb, Wvb, bv, out_V, nullptr,
                                                           F_, D_, D_, nullptr, nullptr);
  transpose_v<<<dim3(F_ / 64, D_ / 64), 256, 0, stream>>>(out_V, Vtb);
  // E = exp(Q K^T / temp) -> out_f (unnormalized), rowsum via atomics
  gemm_bt<2><<<dim3(F_ / 128, B_ / 128), blk, 0, stream>>>(Qb, Kb, nullptr, out_f, nullptr,
                                                           B_, F_, M_, rowsum, temp);
  // normalize f in place + partial x_hat
  xhat_kernel<<<dim3(KS, B_ / 64), dim3(512), 0, stream>>>(out_f, Vtb, rowsum, partial);
  reduce_kernel<<<(B_ * D_ / 4 + 255) / 256, 256, 0, stream>>>(partial, out_xhat, B_ * D_ / 4);
}

// Round 3
// 579.357 us; speedup vs baseline: 1.1005x; 1.1005x over previous
//
#include <hip/hip_runtime.h>
#include <stdint.h>

#define B_ 4096
#define D_ 768
#define F_ 16384
#define M_ 256
#define KS 8

typedef short bf16x8 __attribute__((ext_vector_type(8)));
typedef float f32x4 __attribute__((ext_vector_type(4)));
typedef unsigned short ushort8 __attribute__((ext_vector_type(8)));

__device__ __forceinline__ unsigned short f2bf(float f) {
  union { float f; uint32_t u; } c; c.f = f;
  uint32_t u = c.u;
  uint32_t r = (u + 0x7FFFu + ((u >> 16) & 1u)) >> 16;
  return (unsigned short)r;
}

__device__ __forceinline__ float bf2f(unsigned short s) {
  union { uint32_t u; float f; } c; c.u = ((uint32_t)s) << 16;
  return c.f;
}

__device__ __forceinline__ void gl_lds16(const void* g, void* l) {
  __builtin_amdgcn_global_load_lds(
      (const __attribute__((address_space(1))) unsigned int*)g,
      (__attribute__((address_space(3))) unsigned int*)l, 16, 0, 0);
}

// ---------------- elementwise f32 -> bf16 cast (+optional f32 copy) ----------------
__global__ void cast_kernel(const float* __restrict__ in, unsigned short* __restrict__ out,
                            float* __restrict__ cpy, int n4) {
  int i = blockIdx.x * blockDim.x + threadIdx.x;
  if (i >= n4) return;
  float4 v = reinterpret_cast<const float4*>(in)[i];
  ushort4 u;
  u.x = f2bf(v.x); u.y = f2bf(v.y); u.z = f2bf(v.z); u.w = f2bf(v.w);
  reinterpret_cast<ushort4*>(out)[i] = u;
  if (cpy) reinterpret_cast<float4*>(cpy)[i] = v;
}

// ---------------- gemm_bt: C[M,N] = A[M,K] * B[N,K]^T  (round-1 proven version) ----
// EPI 0: store bf16 (+bias)   EPI 1: store f32 (+bias)   EPI 2: exp(c/temp) -> f32 + rowsum
template <int EPI>
__global__ __launch_bounds__(256, 2) void gemm_bt(
    const unsigned short* __restrict__ A, const unsigned short* __restrict__ Bm,
    const float* __restrict__ bias, float* __restrict__ Cf,
    unsigned short* __restrict__ Cb, int M, int N, int K,
    float* __restrict__ rowsum, const float* __restrict__ tptr) {
  __shared__ unsigned short As[128 * 32];
  __shared__ unsigned short Bs[128 * 32];
  const int tid = threadIdx.x, lane = tid & 63, wave = tid >> 6;
  const int m0 = blockIdx.y * 128, n0 = blockIdx.x * 128;
  const int wr = wave >> 1, wc = wave & 1;
  f32x4 acc[4][4] = {};

  for (int k0 = 0; k0 < K; k0 += 32) {
#pragma unroll
    for (int i = 0; i < 2; ++i) {
      int cb = (i * 4 + wave) * 64;
      int ch = cb + lane;
      int row = ch >> 2, ko = (ch & 3) * 8;
      gl_lds16(A + (size_t)(m0 + row) * K + k0 + ko, (char*)As + (size_t)cb * 16);
      gl_lds16(Bm + (size_t)(n0 + row) * K + k0 + ko, (char*)Bs + (size_t)cb * 16);
    }
    __syncthreads();
    bf16x8 a[4];
#pragma unroll
    for (int m = 0; m < 4; ++m)
      a[m] = *reinterpret_cast<const bf16x8*>(
          &As[(wr * 64 + m * 16 + (lane & 15)) * 32 + (lane >> 4) * 8]);
#pragma unroll
    for (int n = 0; n < 4; ++n) {
      bf16x8 b = *reinterpret_cast<const bf16x8*>(
          &Bs[(wc * 64 + n * 16 + (lane & 15)) * 32 + (lane >> 4) * 8]);
#pragma unroll
      for (int m = 0; m < 4; ++m)
        acc[m][n] = __builtin_amdgcn_mfma_f32_16x16x32_bf16(a[m], b, acc[m][n], 0, 0, 0);
    }
    __syncthreads();
  }

  const int rbase = m0 + wr * 64 + (lane >> 4) * 4;
  const int cbase = n0 + wc * 64 + (lane & 15);
  if (EPI == 2) {
    const float invt = 1.0f / tptr[0];
#pragma unroll
    for (int m = 0; m < 4; ++m) {
      float rs[4] = {0.f, 0.f, 0.f, 0.f};
#pragma unroll
      for (int n = 0; n < 4; ++n) {
        int col = cbase + n * 16;
#pragma unroll
        for (int r = 0; r < 4; ++r) {
          float e = __expf(acc[m][n][r] * invt);
          Cf[(size_t)(rbase + m * 16 + r) * N + col] = e;
          rs[r] += e;
        }
      }
#pragma unroll
      for (int r = 0; r < 4; ++r) {
        float s = rs[r];
        s += __shfl_xor(s, 1);
        s += __shfl_xor(s, 2);
        s += __shfl_xor(s, 4);
        s += __shfl_xor(s, 8);
        if ((lane & 15) == 0) atomicAdd(&rowsum[rbase + m * 16 + r], s);
      }
    }
  } else {
#pragma unroll
    for (int m = 0; m < 4; ++m) {
#pragma unroll
      for (int n = 0; n < 4; ++n) {
        int col = cbase + n * 16;
        float bv = bias[col];
#pragma unroll
        for (int r = 0; r < 4; ++r) {
          float v = acc[m][n][r] + bv;
          size_t idx = (size_t)(rbase + m * 16 + r) * N + col;
          if (EPI == 0) Cb[idx] = f2bf(v);
          else Cf[idx] = v;
        }
      }
    }
  }
}

// ---------------- V[16384,768] f32 -> Vt[768,16384] bf16 (round-1 proven) ----------
__global__ __launch_bounds__(256) void transpose_v(const float* __restrict__ V,
                                                   unsigned short* __restrict__ Vt) {
  __shared__ float t[64][65];
  int r0 = blockIdx.x * 64, c0 = blockIdx.y * 64;
  int tid = threadIdx.x;
  int lr = tid >> 4, lc4 = (tid & 15) * 4;
#pragma unroll
  for (int i = 0; i < 4; ++i) {
    float4 v = *reinterpret_cast<const float4*>(&V[(size_t)(r0 + i * 16 + lr) * D_ + c0 + lc4]);
    t[i * 16 + lr][lc4 + 0] = v.x;
    t[i * 16 + lr][lc4 + 1] = v.y;
    t[i * 16 + lr][lc4 + 2] = v.z;
    t[i * 16 + lr][lc4 + 3] = v.w;
  }
  __syncthreads();
#pragma unroll
  for (int i = 0; i < 4; ++i) {
    int oc = i * 16 + lr;
    ushort4 u;
    u.x = f2bf(t[lc4 + 0][oc]);
    u.y = f2bf(t[lc4 + 1][oc]);
    u.z = f2bf(t[lc4 + 2][oc]);
    u.w = f2bf(t[lc4 + 3][oc]);
    *reinterpret_cast<ushort4*>(&Vt[(size_t)(c0 + oc) * F_ + r0 + lc4]) = u;
  }
}

// ---------------- x_hat v3: race-free KS=8 K-split, full-width 64-row tiles -------
// Each block exclusively owns E[64 rows x 2048 k] (read raw E, write f = E/rowsum,
// stage bf16 A-tile). partial[ks] = (E_chunk @ V_chunk) * diag(1/rowsum), bf16.
// blockIdx: ks = bid&7, rb = bid>>3  =>  same-ks blocks land on one XCD (%8
// round-robin), so each 3.1MB Vt chunk stays in that XCD's L2.
__global__ __launch_bounds__(512, 4) void xhat_kernel(
    float* __restrict__ Ef, const unsigned short* __restrict__ Vt,
    const float* __restrict__ rowsum, unsigned short* __restrict__ partial) {
  __shared__ unsigned short As2[64 * 32];
  __shared__ unsigned short Vs[768 * 32];
  const int tid = threadIdx.x, lane = tid & 63, wave = tid >> 6;
  const int ks = blockIdx.x & 7, rb = blockIdx.x >> 3;
  const int r0 = rb * 64;
  const int kbeg = ks * (F_ / KS);          // 2048-wide K chunk
  const int wr = wave >> 2, wc = wave & 3;  // 2x4 wave grid: 32r x 192c per wave
  const int erow = tid >> 3, ec = (tid & 7) * 4;
  const float inv_f = 1.0f / rowsum[r0 + erow];
  const int q = lane >> 4;
  f32x4 acc[2][12] = {};

  float* ep = Ef + (size_t)(r0 + erow) * F_ + kbeg + ec;
  float4 e = *reinterpret_cast<const float4*>(ep);  // prefetched E for step 0
  const int NSTEP = (F_ / KS) / 32;                 // 64

  for (int si = 0; si < NSTEP; ++si) {
    const int k0 = kbeg + si * 32;
    // ---- stage phase ----
    // write f = E/rowsum (f32, exclusive ownership), pack raw E to bf16 A-tile
    float4 f4 = make_float4(e.x * inv_f, e.y * inv_f, e.z * inv_f, e.w * inv_f);
    *reinterpret_cast<float4*>(ep) = f4;
    ushort4 u;
    u.x = f2bf(e.x); u.y = f2bf(e.y); u.z = f2bf(e.z); u.w = f2bf(e.w);
    {
      int slot = ec >> 3, off = ec & 7;  // 16B-slot index + short offset within
      *reinterpret_cast<ushort4*>(
          &As2[erow * 32 + ((slot ^ ((erow >> 1) & 3)) * 8) + off]) = u;
    }
    // Vt tile [768 x 32] bf16 via global_load_lds, pre-swizzled global source
#pragma unroll
    for (int j = 0; j < 6; ++j) {
      int cb = j * 512 + wave * 64;
      int ch = cb + lane;
      int vrow = ch >> 2;
      int slot = (ch & 3) ^ ((vrow >> 1) & 3);
      gl_lds16(Vt + (size_t)vrow * F_ + k0 + slot * 8, (char*)Vs + (size_t)cb * 16);
    }
    // prefetch next E tile into regs (hides HBM latency under MFMA phase)
    if (si + 1 < NSTEP) e = *reinterpret_cast<const float4*>(ep + 32);
    ep += 32;
    __syncthreads();
    // ---- compute phase ----
    bf16x8 a[2];
#pragma unroll
    for (int m = 0; m < 2; ++m) {
      int R = wr * 32 + m * 16 + (lane & 15);
      a[m] = *reinterpret_cast<const bf16x8*>(&As2[R * 32 + ((q ^ ((R >> 1) & 3)) * 8)]);
    }
#pragma unroll
    for (int n = 0; n < 12; ++n) {
      int C = wc * 192 + n * 16 + (lane & 15);
      bf16x8 b = *reinterpret_cast<const bf16x8*>(&Vs[C * 32 + ((q ^ ((C >> 1) & 3)) * 8)]);
      acc[0][n] = __builtin_amdgcn_mfma_f32_16x16x32_bf16(a[0], b, acc[0][n], 0, 0, 0);
      acc[1][n] = __builtin_amdgcn_mfma_f32_16x16x32_bf16(a[1], b, acc[1][n], 0, 0, 0);
    }
    __syncthreads();
  }

  // ---- epilogue: scale by 1/rowsum, store bf16 partial ----
  unsigned short* P = partial + (size_t)ks * B_ * D_;
#pragma unroll
  for (int m = 0; m < 2; ++m) {
    int rowb = r0 + wr * 32 + m * 16 + q * 4;
#pragma unroll
    for (int r = 0; r < 4; ++r) {
      float inv = 1.0f / rowsum[rowb + r];
      size_t row_off = (size_t)(rowb + r) * D_;
#pragma unroll
      for (int n = 0; n < 12; ++n) {
        int col = wc * 192 + n * 16 + (lane & 15);
        P[row_off + col] = f2bf(acc[m][n][r] * inv);
      }
    }
  }
}

// ---------------- sum KS bf16 partials -> f32 x_hat -------------------------------
__global__ void reduce_kernel(const unsigned short* __restrict__ partial,
                              float* __restrict__ out, int n8) {
  int i = blockIdx.x * blockDim.x + threadIdx.x;
  if (i >= n8) return;
  size_t base = (size_t)i * 8;
  float s[8] = {0.f, 0.f, 0.f, 0.f, 0.f, 0.f, 0.f, 0.f};
#pragma unroll
  for (int ks = 0; ks < KS; ++ks) {
    ushort8 v = *reinterpret_cast<const ushort8*>(&partial[(size_t)ks * B_ * D_ + base]);
#pragma unroll
    for (int j = 0; j < 8; ++j) s[j] += bf2f(v[j]);
  }
  float4 o0 = make_float4(s[0], s[1], s[2], s[3]);
  float4 o1 = make_float4(s[4], s[5], s[6], s[7]);
  *reinterpret_cast<float4*>(&out[base]) = o0;
  *reinterpret_cast<float4*>(&out[base + 4]) = o1;
}

extern "C" void kernel_launch(void* const* d_in, const int* in_sizes, int n_in,
                              void* d_out, int out_size, void* d_ws, size_t ws_size,
                              hipStream_t stream) {
  const float* x = (const float*)d_in[0];
  const float* mb = (const float*)d_in[1];
  const float* Wq = (const float*)d_in[2];
  const float* bq = (const float*)d_in[3];
  const float* Wk = (const float*)d_in[4];
  const float* bk = (const float*)d_in[5];
  const float* Wv = (const float*)d_in[6];
  const float* bv = (const float*)d_in[7];
  const float* temp = (const float*)d_in[8];

  float* out_x = (float*)d_out;
  float* out_xhat = out_x + (size_t)B_ * D_;
  float* out_f = out_xhat + (size_t)B_ * D_;
  float* out_V = out_f + (size_t)B_ * F_;

  char* ws = (char*)d_ws;
  unsigned short* xb  = (unsigned short*)(ws + 0);         // 4096*768*2   = 6291456
  unsigned short* mbb = (unsigned short*)(ws + 6291456);   // 16384*768*2  = 25165824
  unsigned short* Wqb = (unsigned short*)(ws + 31457280);  // 256*768*2    = 393216
  unsigned short* Wkb = (unsigned short*)(ws + 31850496);  // 393216
  unsigned short* Wvb = (unsigned short*)(ws + 32243712);  // 768*768*2    = 1179648
  unsigned short* Qb  = (unsigned short*)(ws + 33423360);  // 4096*256*2   = 2097152
  unsigned short* Kb  = (unsigned short*)(ws + 35520512);  // 16384*256*2  = 8388608
  unsigned short* Vtb = (unsigned short*)(ws + 43909120);  // 768*16384*2  = 25165824
  float* rowsum       = (float*)(ws + 69074944);           // 4096*4       = 16384
  unsigned short* partial = (unsigned short*)(ws + 69091328); // 8*4096*768*2 = 50331648
  // total ws use: ~119.4 MB (same as round-1-proven footprint)

  hipMemsetAsync(rowsum, 0, B_ * sizeof(float), stream);

  cast_kernel<<<(B_ * D_ / 4 + 255) / 256, 256, 0, stream>>>(x, xb, out_x, B_ * D_ / 4);
  cast_kernel<<<(F_ * D_ / 4 + 255) / 256, 256, 0, stream>>>(mb, mbb, nullptr, F_ * D_ / 4);
  cast_kernel<<<(M_ * D_ / 4 + 255) / 256, 256, 0, stream>>>(Wq, Wqb, nullptr, M_ * D_ / 4);
  cast_kernel<<<(M_ * D_ / 4 + 255) / 256, 256, 0, stream>>>(Wk, Wkb, nullptr, M_ * D_ / 4);
  cast_kernel<<<(D_ * D_ / 4 + 255) / 256, 256, 0, stream>>>(Wv, Wvb, nullptr, D_ * D_ / 4);

  dim3 blk(256);
  // Q = x @ Wq^T + bq  -> Qb (bf16)
  gemm_bt<0><<<dim3(M_ / 128, B_ / 128), blk, 0, stream>>>(xb, Wqb, bq, nullptr, Qb,
                                                           B_, M_, D_, nullptr, nullptr);
  // K = mb @ Wk^T + bk -> Kb (bf16)
  gemm_bt<0><<<dim3(M_ / 128, F_ / 128), blk, 0, stream>>>(mbb, Wkb, bk, nullptr, Kb,
                                                           F_, M_, D_, nullptr, nullptr);
  // V = mb @ Wv^T + bv -> out_V (f32)
  gemm_bt<1><<<dim3(D_ / 128, F_ / 128), blk, 0, stream>>>(mbb, Wvb, bv, out_V, nullptr,
                                                           F_, D_, D_, nullptr, nullptr);
  transpose_v<<<dim3(F_ / 64, D_ / 64), 256, 0, stream>>>(out_V, Vtb);
  // E = exp(Q K^T / temp) -> out_f (unnormalized), rowsum via atomics
  gemm_bt<2><<<dim3(F_ / 128, B_ / 128), blk, 0, stream>>>(Qb, Kb, nullptr, out_f, nullptr,
                                                           B_, F_, M_, rowsum, temp);
  // normalize f in place + bf16 partial x_hat
  xhat_kernel<<<dim3(512), dim3(512), 0, stream>>>(out_f, Vtb, rowsum, partial);
  reduce_kernel<<<(B_ * D_ / 8 + 255) / 256, 256, 0, stream>>>(partial, out_xhat, B_ * D_ / 8);
}

// Round 4
// 539.290 us; speedup vs baseline: 1.1822x; 1.0743x over previous
//
#include <hip/hip_runtime.h>
#include <stdint.h>

#define B_ 4096
#define D_ 768
#define F_ 16384
#define M_ 256
#define KS 8

typedef short bf16x8 __attribute__((ext_vector_type(8)));
typedef float f32x4 __attribute__((ext_vector_type(4)));
typedef unsigned short ushort8 __attribute__((ext_vector_type(8)));

__device__ __forceinline__ unsigned short f2bf(float f) {
  union { float f; uint32_t u; } c; c.f = f;
  uint32_t u = c.u;
  uint32_t r = (u + 0x7FFFu + ((u >> 16) & 1u)) >> 16;
  return (unsigned short)r;
}

__device__ __forceinline__ float bf2f(unsigned short s) {
  union { uint32_t u; float f; } c; c.u = ((uint32_t)s) << 16;
  return c.f;
}

__device__ __forceinline__ void gl_lds16(const void* g, void* l) {
  __builtin_amdgcn_global_load_lds(
      (const __attribute__((address_space(1))) unsigned int*)g,
      (__attribute__((address_space(3))) unsigned int*)l, 16, 0, 0);
}

// ---------------- elementwise f32 -> bf16 cast (+optional f32 copy) ----------------
__global__ void cast_kernel(const float* __restrict__ in, unsigned short* __restrict__ out,
                            float* __restrict__ cpy, int n4) {
  int i = blockIdx.x * blockDim.x + threadIdx.x;
  if (i >= n4) return;
  float4 v = reinterpret_cast<const float4*>(in)[i];
  ushort4 u;
  u.x = f2bf(v.x); u.y = f2bf(v.y); u.z = f2bf(v.z); u.w = f2bf(v.w);
  reinterpret_cast<ushort4*>(out)[i] = u;
  if (cpy) reinterpret_cast<float4*>(cpy)[i] = v;
}

// ---------------- gemm_bt: C[M,N] = A[M,K] * B[N,K]^T  (round-1 proven version) ----
// EPI 0: store bf16 (+bias)   EPI 1: store f32 (+bias)   EPI 2: exp(c/temp) -> f32 + rowsum
template <int EPI>
__global__ __launch_bounds__(256, 2) void gemm_bt(
    const unsigned short* __restrict__ A, const unsigned short* __restrict__ Bm,
    const float* __restrict__ bias, float* __restrict__ Cf,
    unsigned short* __restrict__ Cb, int M, int N, int K,
    float* __restrict__ rowsum, const float* __restrict__ tptr) {
  __shared__ unsigned short As[128 * 32];
  __shared__ unsigned short Bs[128 * 32];
  const int tid = threadIdx.x, lane = tid & 63, wave = tid >> 6;
  const int m0 = blockIdx.y * 128, n0 = blockIdx.x * 128;
  const int wr = wave >> 1, wc = wave & 1;
  f32x4 acc[4][4] = {};

  for (int k0 = 0; k0 < K; k0 += 32) {
#pragma unroll
    for (int i = 0; i < 2; ++i) {
      int cb = (i * 4 + wave) * 64;
      int ch = cb + lane;
      int row = ch >> 2, ko = (ch & 3) * 8;
      gl_lds16(A + (size_t)(m0 + row) * K + k0 + ko, (char*)As + (size_t)cb * 16);
      gl_lds16(Bm + (size_t)(n0 + row) * K + k0 + ko, (char*)Bs + (size_t)cb * 16);
    }
    __syncthreads();
    bf16x8 a[4];
#pragma unroll
    for (int m = 0; m < 4; ++m)
      a[m] = *reinterpret_cast<const bf16x8*>(
          &As[(wr * 64 + m * 16 + (lane & 15)) * 32 + (lane >> 4) * 8]);
#pragma unroll
    for (int n = 0; n < 4; ++n) {
      bf16x8 b = *reinterpret_cast<const bf16x8*>(
          &Bs[(wc * 64 + n * 16 + (lane & 15)) * 32 + (lane >> 4) * 8]);
#pragma unroll
      for (int m = 0; m < 4; ++m)
        acc[m][n] = __builtin_amdgcn_mfma_f32_16x16x32_bf16(a[m], b, acc[m][n], 0, 0, 0);
    }
    __syncthreads();
  }

  const int rbase = m0 + wr * 64 + (lane >> 4) * 4;
  const int cbase = n0 + wc * 64 + (lane & 15);
  if (EPI == 2) {
    const float invt = 1.0f / tptr[0];
#pragma unroll
    for (int m = 0; m < 4; ++m) {
      float rs[4] = {0.f, 0.f, 0.f, 0.f};
#pragma unroll
      for (int n = 0; n < 4; ++n) {
        int col = cbase + n * 16;
#pragma unroll
        for (int r = 0; r < 4; ++r) {
          float e = __expf(acc[m][n][r] * invt);
          Cf[(size_t)(rbase + m * 16 + r) * N + col] = e;
          rs[r] += e;
        }
      }
#pragma unroll
      for (int r = 0; r < 4; ++r) {
        float s = rs[r];
        s += __shfl_xor(s, 1);
        s += __shfl_xor(s, 2);
        s += __shfl_xor(s, 4);
        s += __shfl_xor(s, 8);
        if ((lane & 15) == 0) atomicAdd(&rowsum[rbase + m * 16 + r], s);
      }
    }
  } else {
#pragma unroll
    for (int m = 0; m < 4; ++m) {
#pragma unroll
      for (int n = 0; n < 4; ++n) {
        int col = cbase + n * 16;
        float bv = bias[col];
#pragma unroll
        for (int r = 0; r < 4; ++r) {
          float v = acc[m][n][r] + bv;
          size_t idx = (size_t)(rbase + m * 16 + r) * N + col;
          if (EPI == 0) Cb[idx] = f2bf(v);
          else Cf[idx] = v;
        }
      }
    }
  }
}

// ---------------- V[16384,768] f32 -> Vt_tiled bf16 --------------------------------
// Tile t (k-range t*32..t*32+32): 48KB contiguous block. Interior layout matches
// xhat's LDS image exactly (XOR slot-swizzle PRE-APPLIED):
//   Vt_tiled[t*24576 + d*32 + s*8 + o] = bf16( V[t*32 + (s^((d>>1)&3))*8 + o][d] )
// so xhat's global_load_lds reads are perfectly contiguous 1KB streams.
__global__ __launch_bounds__(256) void vt_tiler(const float* __restrict__ V,
                                                unsigned short* __restrict__ Vt_tiled) {
  __shared__ unsigned short T[768][36];  // [d][k_local], +4 pad shorts
  const int t = blockIdx.x, k0 = t * 32, tid = threadIdx.x;
  const int kl = tid >> 3, c0 = (tid & 7) * 4;  // 32 k-rows x 32 cols per pass
  for (int cb = 0; cb < 768; cb += 32) {
    float4 v = *reinterpret_cast<const float4*>(&V[(size_t)(k0 + kl) * D_ + cb + c0]);
    T[cb + c0 + 0][kl] = f2bf(v.x);
    T[cb + c0 + 1][kl] = f2bf(v.y);
    T[cb + c0 + 2][kl] = f2bf(v.z);
    T[cb + c0 + 3][kl] = f2bf(v.w);
  }
  __syncthreads();
  for (int d = tid; d < 768; d += 256) {
    const int x = (d >> 1) & 3;
    unsigned short* o = Vt_tiled + (size_t)t * 24576 + d * 32;
#pragma unroll
    for (int s = 0; s < 4; ++s) {
      // 8B LDS loads (row stride 72B is 8B-aligned), 8B global stores
      ushort4 lo = *reinterpret_cast<const ushort4*>(&T[d][(s ^ x) * 8]);
      ushort4 hi = *reinterpret_cast<const ushort4*>(&T[d][(s ^ x) * 8 + 4]);
      *reinterpret_cast<ushort4*>(o + s * 8) = lo;
      *reinterpret_cast<ushort4*>(o + s * 8 + 4) = hi;
    }
  }
}

// ---------------- x_hat v4: tiled-Vt contiguous staging ---------------------------
// Each block exclusively owns E[64 rows x 2048 k] (read raw E, write f = E/rowsum,
// stage bf16 A-tile). partial[ks] = (E_chunk @ V_chunk) * diag(1/rowsum), bf16.
// ks = bid&7 -> same-ks blocks land on one XCD (%8 round-robin); each XCD streams
// its 3.1MB of Vt_tiled from L2/L3 in fully contiguous 1KB-per-instr gl_lds.
__global__ __launch_bounds__(512, 4) void xhat_kernel(
    float* __restrict__ Ef, const unsigned short* __restrict__ Vt_tiled,
    const float* __restrict__ rowsum, unsigned short* __restrict__ partial) {
  __shared__ unsigned short As2[64 * 32];
  __shared__ unsigned short Vs[768 * 32];
  const int tid = threadIdx.x, lane = tid & 63, wave = tid >> 6;
  const int ks = blockIdx.x & 7, rb = blockIdx.x >> 3;
  const int r0 = rb * 64;
  const int kbeg = ks * (F_ / KS);          // 2048-wide K chunk
  const int wr = wave >> 2, wc = wave & 3;  // 2x4 wave grid: 32r x 192c per wave
  const int erow = tid >> 3, ec = (tid & 7) * 4;
  const float inv_f = 1.0f / rowsum[r0 + erow];
  const int q = lane >> 4;
  f32x4 acc[2][12] = {};

  float* ep = Ef + (size_t)(r0 + erow) * F_ + kbeg + ec;
  float4 e = *reinterpret_cast<const float4*>(ep);  // E for step 0
  const int NSTEP = (F_ / KS) / 32;                 // 64
  // per-wave/lane constant base into the tiled-V stream (shorts)
  const unsigned short* vt_base =
      Vt_tiled + (size_t)(kbeg >> 5) * 24576 + wave * 512 + lane * 8;

  for (int si = 0; si < NSTEP; ++si) {
    // ---- stage phase ----
    // write f = E/rowsum (f32, exclusive ownership), pack raw E to bf16 A-tile
    float4 f4 = make_float4(e.x * inv_f, e.y * inv_f, e.z * inv_f, e.w * inv_f);
    *reinterpret_cast<float4*>(ep) = f4;
    ushort4 u;
    u.x = f2bf(e.x); u.y = f2bf(e.y); u.z = f2bf(e.z); u.w = f2bf(e.w);
    {
      int slot = ec >> 3, off = ec & 7;
      *reinterpret_cast<ushort4*>(
          &As2[erow * 32 + ((slot ^ ((erow >> 1) & 3)) * 8) + off]) = u;
    }
    // Vs tile: 6 fully-contiguous 1KB gl_lds per wave from the tiled stream
    const unsigned short* vs_src = vt_base + (size_t)si * 24576;
#pragma unroll
    for (int j = 0; j < 6; ++j)
      gl_lds16(vs_src + j * 4096, (char*)Vs + (size_t)(j * 512 + wave * 64) * 16);
    __syncthreads();
    // ---- compute phase ----
    // E prefetch for next step issued here: its latency hides under ds_read+MFMA
    // and drains at the second barrier instead of the staging barrier.
    if (si + 1 < NSTEP) e = *reinterpret_cast<const float4*>(ep + 32);
    ep += 32;
    bf16x8 a[2];
#pragma unroll
    for (int m = 0; m < 2; ++m) {
      int R = wr * 32 + m * 16 + (lane & 15);
      a[m] = *reinterpret_cast<const bf16x8*>(&As2[R * 32 + ((q ^ ((R >> 1) & 3)) * 8)]);
    }
#pragma unroll
    for (int n = 0; n < 12; ++n) {
      int C = wc * 192 + n * 16 + (lane & 15);
      bf16x8 b = *reinterpret_cast<const bf16x8*>(&Vs[C * 32 + ((q ^ ((C >> 1) & 3)) * 8)]);
      acc[0][n] = __builtin_amdgcn_mfma_f32_16x16x32_bf16(a[0], b, acc[0][n], 0, 0, 0);
      acc[1][n] = __builtin_amdgcn_mfma_f32_16x16x32_bf16(a[1], b, acc[1][n], 0, 0, 0);
    }
    __syncthreads();
  }

  // ---- epilogue: scale by 1/rowsum, store bf16 partial ----
  unsigned short* P = partial + (size_t)ks * B_ * D_;
#pragma unroll
  for (int m = 0; m < 2; ++m) {
    int rowb = r0 + wr * 32 + m * 16 + q * 4;
#pragma unroll
    for (int r = 0; r < 4; ++r) {
      float inv = 1.0f / rowsum[rowb + r];
      size_t row_off = (size_t)(rowb + r) * D_;
#pragma unroll
      for (int n = 0; n < 12; ++n) {
        int col = wc * 192 + n * 16 + (lane & 15);
        P[row_off + col] = f2bf(acc[m][n][r] * inv);
      }
    }
  }
}

// ---------------- sum KS bf16 partials -> f32 x_hat -------------------------------
__global__ void reduce_kernel(const unsigned short* __restrict__ partial,
                              float* __restrict__ out, int n8) {
  int i = blockIdx.x * blockDim.x + threadIdx.x;
  if (i >= n8) return;
  size_t base = (size_t)i * 8;
  float s[8] = {0.f, 0.f, 0.f, 0.f, 0.f, 0.f, 0.f, 0.f};
#pragma unroll
  for (int ks = 0; ks < KS; ++ks) {
    ushort8 v = *reinterpret_cast<const ushort8*>(&partial[(size_t)ks * B_ * D_ + base]);
#pragma unroll
    for (int j = 0; j < 8; ++j) s[j] += bf2f(v[j]);
  }
  float4 o0 = make_float4(s[0], s[1], s[2], s[3]);
  float4 o1 = make_float4(s[4], s[5], s[6], s[7]);
  *reinterpret_cast<float4*>(&out[base]) = o0;
  *reinterpret_cast<float4*>(&out[base + 4]) = o1;
}

extern "C" void kernel_launch(void* const* d_in, const int* in_sizes, int n_in,
                              void* d_out, int out_size, void* d_ws, size_t ws_size,
                              hipStream_t stream) {
  const float* x = (const float*)d_in[0];
  const float* mb = (const float*)d_in[1];
  const float* Wq = (const float*)d_in[2];
  const float* bq = (const float*)d_in[3];
  const float* Wk = (const float*)d_in[4];
  const float* bk = (const float*)d_in[5];
  const float* Wv = (const float*)d_in[6];
  const float* bv = (const float*)d_in[7];
  const float* temp = (const float*)d_in[8];

  float* out_x = (float*)d_out;
  float* out_xhat = out_x + (size_t)B_ * D_;
  float* out_f = out_xhat + (size_t)B_ * D_;
  float* out_V = out_f + (size_t)B_ * F_;

  char* ws = (char*)d_ws;
  unsigned short* xb  = (unsigned short*)(ws + 0);         // 4096*768*2   = 6291456
  unsigned short* mbb = (unsigned short*)(ws + 6291456);   // 16384*768*2  = 25165824
  unsigned short* Wqb = (unsigned short*)(ws + 31457280);  // 256*768*2    = 393216
  unsigned short* Wkb = (unsigned short*)(ws + 31850496);  // 393216
  unsigned short* Wvb = (unsigned short*)(ws + 32243712);  // 768*768*2    = 1179648
  unsigned short* Qb  = (unsigned short*)(ws + 33423360);  // 4096*256*2   = 2097152
  unsigned short* Kb  = (unsigned short*)(ws + 35520512);  // 16384*256*2  = 8388608
  unsigned short* Vtt = (unsigned short*)(ws + 43909120);  // 768*16384*2  = 25165824 (tiled)
  float* rowsum       = (float*)(ws + 69074944);           // 4096*4       = 16384
  unsigned short* partial = (unsigned short*)(ws + 69091328); // 8*4096*768*2 = 50331648
  // total ws use: ~119.4 MB (unchanged footprint)

  hipMemsetAsync(rowsum, 0, B_ * sizeof(float), stream);

  cast_kernel<<<(B_ * D_ / 4 + 255) / 256, 256, 0, stream>>>(x, xb, out_x, B_ * D_ / 4);
  cast_kernel<<<(F_ * D_ / 4 + 255) / 256, 256, 0, stream>>>(mb, mbb, nullptr, F_ * D_ / 4);
  cast_kernel<<<(M_ * D_ / 4 + 255) / 256, 256, 0, stream>>>(Wq, Wqb, nullptr, M_ * D_ / 4);
  cast_kernel<<<(M_ * D_ / 4 + 255) / 256, 256, 0, stream>>>(Wk, Wkb, nullptr, M_ * D_ / 4);
  cast_kernel<<<(D_ * D_ / 4 + 255) / 256, 256, 0, stream>>>(Wv, Wvb, nullptr, D_ * D_ / 4);

  dim3 blk(256);
  // Q = x @ Wq^T + bq  -> Qb (bf16)
  gemm_bt<0><<<dim3(M_ / 128, B_ / 128), blk, 0, stream>>>(xb, Wqb, bq, nullptr, Qb,
                                                           B_, M_, D_, nullptr, nullptr);
  // K = mb @ Wk^T + bk -> Kb (bf16)
  gemm_bt<0><<<dim3(M_ / 128, F_ / 128), blk, 0, stream>>>(mbb, Wkb, bk, nullptr, Kb,
                                                           F_, M_, D_, nullptr, nullptr);
  // V = mb @ Wv^T + bv -> out_V (f32)
  gemm_bt<1><<<dim3(D_ / 128, F_ / 128), blk, 0, stream>>>(mbb, Wvb, bv, out_V, nullptr,
                                                           F_, D_, D_, nullptr, nullptr);
  // V -> tiled bf16 stream for xhat staging
  vt_tiler<<<dim3(F_ / 32), 256, 0, stream>>>(out_V, Vtt);
  // E = exp(Q K^T / temp) -> out_f (unnormalized), rowsum via atomics
  gemm_bt<2><<<dim3(F_ / 128, B_ / 128), blk, 0, stream>>>(Qb, Kb, nullptr, out_f, nullptr,
                                                           B_, F_, M_, rowsum, temp);
  // normalize f in place + bf16 partial x_hat
  xhat_kernel<<<dim3(512), dim3(512), 0, stream>>>(out_f, Vtt, rowsum, partial);
  reduce_kernel<<<(B_ * D_ / 8 + 255) / 256, 256, 0, stream>>>(partial, out_xhat, B_ * D_ / 8);
}